// Round 5
// baseline (72.848 us; speedup 1.0000x reference)
//
#include <hip/hip_runtime.h>

// PackedAvgPool1d, kernel == stride == 2, H = 1024 (fixed by reference).
// Outputs (flat fp32, concatenated): y[new_total*H], new_seq_lens[B], new_cu[B+1].
//
// Persistent kernel, TWO ADJACENT OUTPUT ROWS PER WAVE per iteration: the wave
// issues all 16 sequential 1KB loads (typically one contiguous 16KB input
// span) before any store, then writes 8KB sequentially -- fewer HBM
// read<->write turnarounds, deeper MLP. Segment table (B <= 64) in-register:
// coalesced seq_lens load + shfl_up scans; row->segment via ballot+popc.
// Nontemporal float4 (zero reuse).

#define HDIM 1024
#define F4_PER_ROW 256   // HDIM/4
#define WPB 4            // waves per block
#define RPW 2            // rows per wave per iteration
#define RPG (WPB * RPW)  // rows per block-iteration

typedef __attribute__((ext_vector_type(4))) float f4;

__global__ __launch_bounds__(256) void pool_fused_kernel(
    const f4* __restrict__ xv,
    const int* __restrict__ seq_lens,
    int B, int new_total,
    f4* __restrict__ yv,
    float* __restrict__ out_lens,
    float* __restrict__ out_cu)
{
    const int tid  = threadIdx.x;
    const int lane = tid & 63;
    const int wid  = tid >> 6;     // wave id 0..3

    // --- per-wave segment table (B <= 64) ---
    int L  = (lane < B) ? seq_lens[lane] : 0;
    int nl = (L + 1) >> 1;            // new_len = ceil(L/2)
    int S = nl, C = L;                // inclusive scans of nl and L
    #pragma unroll
    for (int d = 1; d < 64; d <<= 1) {
        int s2 = __shfl_up(S, d, 64);
        int c2 = __shfl_up(C, d, 64);
        if (lane >= d) { S += s2; C += c2; }
    }

    // block 0, wave 0 writes the fp32 meta tail
    if (blockIdx.x == 0 && tid < 64) {
        if (lane < B) {
            out_lens[lane]   = (float)nl;
            out_cu[lane + 1] = (float)S;
        }
        if (lane == 0) out_cu[0] = 0.0f;
    }

    const int ngroups = (new_total + RPG - 1) / RPG;

    for (int g = blockIdx.x; g < ngroups; g += gridDim.x) {
        const int rbase = g * RPG + wid * RPW;   // this wave's first row
        if (rbase >= new_total) continue;        // wave-uniform

        bool rv[RPW], pr[RPW];
        f4 v0[RPW][4], v1[RPW][4];

        // phase 1: locate + issue ALL loads for both rows
        #pragma unroll
        for (int q = 0; q < RPW; ++q) {
            const int r = rbase + q;
            rv[q] = (r < new_total);
            const int rr = rv[q] ? r : 0;
            const int b   = (int)__popcll(__ballot(S <= rr));
            const int Sb  = __shfl(S,  b, 64);
            const int nlb = __shfl(nl, b, 64);
            const int Cb  = __shfl(C,  b, 64);
            const int Lb  = __shfl(L,  b, 64);
            const int j   = rr - (Sb - nlb);       // row within segment
            const int i0  = (Cb - Lb) + 2 * j;     // input row index
            pr[q] = (2 * j + 1 < Lb);              // wave-uniform

            const f4* r0 = xv + (size_t)i0 * F4_PER_ROW + lane;
            if (rv[q]) {
                #pragma unroll
                for (int c = 0; c < 4; ++c)
                    v0[q][c] = __builtin_nontemporal_load(r0 + c * 64);
                if (pr[q]) {
                    #pragma unroll
                    for (int c = 0; c < 4; ++c)
                        v1[q][c] = __builtin_nontemporal_load(r0 + F4_PER_ROW + c * 64);
                }
            }
        }

        // phase 2: combine + store both rows
        #pragma unroll
        for (int q = 0; q < RPW; ++q) {
            if (!rv[q]) continue;
            if (pr[q]) {
                #pragma unroll
                for (int c = 0; c < 4; ++c)
                    v0[q][c] = (v0[q][c] + v1[q][c]) * 0.5f;
            }
            f4* o = yv + (size_t)(rbase + q) * F4_PER_ROW + lane;
            #pragma unroll
            for (int c = 0; c < 4; ++c)
                __builtin_nontemporal_store(v0[q][c], o + c * 64);
        }
    }
}

extern "C" void kernel_launch(void* const* d_in, const int* in_sizes, int n_in,
                              void* d_out, int out_size, void* d_ws, size_t ws_size,
                              hipStream_t stream) {
    const f4*  xv       = (const f4*)d_in[0];
    const int* seq_lens = (const int*)d_in[1];
    // d_in[2] = cu_seq_lens (recomputed in-wave), d_in[3] = max_seq_len
    // (general path is exact for max_seq_len==1 too).

    const int B = in_sizes[1];                       // 64 (<= wave width)
    const int new_total = (out_size - (2 * B + 1)) / HDIM;

    float* y        = (float*)d_out;
    float* out_lens = y + (size_t)new_total * HDIM;
    float* out_cu   = out_lens + B;

    const int ngroups = (new_total + RPG - 1) / RPG;
    const int grid = ngroups < 2048 ? ngroups : 2048;
    hipLaunchKernelGGL(pool_fused_kernel, dim3(grid), dim3(256), 0, stream,
                       xv, seq_lens, B, new_total, (f4*)y, out_lens, out_cu);
}